// Round 1
// baseline (4933.685 us; speedup 1.0000x reference)
//
#include <hip/hip_runtime.h>

// RGCN 3-layer forward on MI355X.
// Strategy: per layer, out = x@root + bias; for each relation r:
//   T = x@W[r]  (GEMM), then scatter out[dst] += T[src] * invcnt[r][dst].
// invcnt computed once per call (depends only on edge_type/dst).
// f32 vector GEMM baseline (no fp32 MFMA on CDNA4); bf16 MFMA comes later.

#define D 384
#define BM 64
#define BN 64
#define BK 16

__global__ __launch_bounds__(256) void gemm_bias_f32(
    const float* __restrict__ A, const float* __restrict__ B,
    const float* __restrict__ bias, float* __restrict__ C, int M)
{
    // A: [M, D] row-major; B: [D, D] row-major (k rows, n cols); C: [M, D]
    __shared__ float As[BK][BM];      // transposed A tile: As[k][m]
    __shared__ float Bs[BK][BN + 4];  // Bs[k][n], padded (16B-aligned rows)

    const int tid = threadIdx.x;
    const int bm = blockIdx.x * BM;
    const int bn = blockIdx.y * BN;
    const int ty = tid >> 4;          // 0..15
    const int tx = tid & 15;          // 0..15

    // A-tile load mapping: 64 rows x 16 k, float4 per thread
    const int ar = tid >> 2;          // 0..63  (m within tile)
    const int ak = (tid & 3) << 2;    // 0,4,8,12 (k within tile)
    // B-tile load mapping: 16 k-rows x 64 n, float4 per thread
    const int bkr = tid >> 4;         // 0..15 (k within tile)
    const int bnc = (tid & 15) << 2;  // 0..60 (n within tile)

    const int arow = bm + ar;

    float acc[4][4] = {};

    for (int k0 = 0; k0 < D; k0 += BK) {
        float4 av = make_float4(0.f, 0.f, 0.f, 0.f);
        if (arow < M) av = *(const float4*)(A + (size_t)arow * D + k0 + ak);
        const float4 bv = *(const float4*)(B + (size_t)(k0 + bkr) * D + bn + bnc);

        __syncthreads();
        As[ak + 0][ar] = av.x;
        As[ak + 1][ar] = av.y;
        As[ak + 2][ar] = av.z;
        As[ak + 3][ar] = av.w;
        *(float4*)(&Bs[bkr][bnc]) = bv;
        __syncthreads();

#pragma unroll
        for (int k = 0; k < BK; ++k) {
            const float a0 = As[k][ty * 4 + 0];
            const float a1 = As[k][ty * 4 + 1];
            const float a2 = As[k][ty * 4 + 2];
            const float a3 = As[k][ty * 4 + 3];
            const float b0 = Bs[k][tx * 4 + 0];
            const float b1 = Bs[k][tx * 4 + 1];
            const float b2 = Bs[k][tx * 4 + 2];
            const float b3 = Bs[k][tx * 4 + 3];
            acc[0][0] += a0 * b0; acc[0][1] += a0 * b1; acc[0][2] += a0 * b2; acc[0][3] += a0 * b3;
            acc[1][0] += a1 * b0; acc[1][1] += a1 * b1; acc[1][2] += a1 * b2; acc[1][3] += a1 * b3;
            acc[2][0] += a2 * b0; acc[2][1] += a2 * b1; acc[2][2] += a2 * b2; acc[2][3] += a2 * b3;
            acc[3][0] += a3 * b0; acc[3][1] += a3 * b1; acc[3][2] += a3 * b2; acc[3][3] += a3 * b3;
        }
    }

    float badd[4] = {0.f, 0.f, 0.f, 0.f};
    if (bias) {
#pragma unroll
        for (int j = 0; j < 4; ++j) badd[j] = bias[bn + tx * 4 + j];
    }
#pragma unroll
    for (int i = 0; i < 4; ++i) {
        const int row = bm + ty * 4 + i;
        if (row < M) {
            float* cp = C + (size_t)row * D + bn + tx * 4;
            float4 v;
            v.x = acc[i][0] + badd[0];
            v.y = acc[i][1] + badd[1];
            v.z = acc[i][2] + badd[2];
            v.w = acc[i][3] + badd[3];
            *(float4*)cp = v;
        }
    }
}

__global__ __launch_bounds__(256) void count_edges(
    const int* __restrict__ dst, const int* __restrict__ et,
    float* __restrict__ cnt, int E, int N)
{
    const int e = blockIdx.x * blockDim.x + threadIdx.x;
    if (e < E) atomicAdd(&cnt[(size_t)et[e] * N + dst[e]], 1.0f);
}

__global__ __launch_bounds__(256) void finalize_cnt(float* __restrict__ cnt, int n)
{
    const int i = blockIdx.x * blockDim.x + threadIdx.x;
    if (i < n) cnt[i] = 1.0f / fmaxf(cnt[i], 1.0f);
}

__global__ __launch_bounds__(256) void scatter_rel(
    const float* __restrict__ T, const int* __restrict__ src,
    const int* __restrict__ dst, const int* __restrict__ et,
    const float* __restrict__ invc, float* __restrict__ out, int E, int rel)
{
    const int idx = blockIdx.x * blockDim.x + threadIdx.x;
    const int e = idx / (D / 4);
    if (e >= E) return;
    if (et[e] != rel) return;
    const int j = (idx - e * (D / 4)) << 2;
    const int s = src[e];
    const int d = dst[e];
    const float ic = invc[d];
    const float4 v = *(const float4*)(T + (size_t)s * D + j);
    float* o = out + (size_t)d * D + j;
    atomicAdd(o + 0, v.x * ic);
    atomicAdd(o + 1, v.y * ic);
    atomicAdd(o + 2, v.z * ic);
    atomicAdd(o + 3, v.w * ic);
}

__global__ __launch_bounds__(256) void relu_kernel(float* __restrict__ x, int n4)
{
    const int i = blockIdx.x * blockDim.x + threadIdx.x;
    if (i < n4) {
        float4 v = ((float4*)x)[i];
        v.x = fmaxf(v.x, 0.f);
        v.y = fmaxf(v.y, 0.f);
        v.z = fmaxf(v.z, 0.f);
        v.w = fmaxf(v.w, 0.f);
        ((float4*)x)[i] = v;
    }
}

static void run_layer(const float* xin, float* xout, const float* W,
                      const float* root, const float* bias,
                      const int* src, const int* dst, const int* et,
                      const float* invcnt, float* T, int M, int E, bool relu,
                      hipStream_t stream)
{
    dim3 gg((M + BM - 1) / BM, D / BN);
    dim3 gb(256);
    gemm_bias_f32<<<gg, gb, 0, stream>>>(xin, root, bias, xout, M);
    const int total = E * (D / 4);
    for (int r = 0; r < 2; ++r) {
        gemm_bias_f32<<<gg, gb, 0, stream>>>(xin, W + (size_t)r * D * D, nullptr, T, M);
        scatter_rel<<<(total + 255) / 256, 256, 0, stream>>>(
            T, src, dst, et, invcnt + (size_t)r * M, xout, E, r);
    }
    if (relu) {
        const int n4 = M * D / 4;
        relu_kernel<<<(n4 + 255) / 256, 256, 0, stream>>>(xout, n4);
    }
}

extern "C" void kernel_launch(void* const* d_in, const int* in_sizes, int n_in,
                              void* d_out, int out_size, void* d_ws, size_t ws_size,
                              hipStream_t stream)
{
    const float* emb  = (const float*)d_in[0];
    const int*   eidx = (const int*)d_in[1];   // [2, E]
    const int*   et   = (const int*)d_in[2];   // [E]
    const float* W1   = (const float*)d_in[3];
    const float* root1= (const float*)d_in[4];
    const float* bias1= (const float*)d_in[5];
    const float* W2   = (const float*)d_in[6];
    const float* root2= (const float*)d_in[7];
    const float* bias2= (const float*)d_in[8];
    const float* W3   = (const float*)d_in[9];
    const float* root3= (const float*)d_in[10];
    const float* bias3= (const float*)d_in[11];

    float* out = (float*)d_out;

    const int M = in_sizes[0] / D;   // 50000 nodes
    const int E = in_sizes[1] / 2;   // 200000 edges
    const int* src = eidx;
    const int* dstv = eidx + E;

    // Workspace layout: Y [M*D] | T [M*D] | invcnt [2*M]
    float* Y = (float*)d_ws;
    float* T = Y + (size_t)M * D;
    float* invcnt = T + (size_t)M * D;

    // Edge counts per (relation, dst) -> 1/max(cnt,1). Same for all layers.
    hipMemsetAsync(invcnt, 0, (size_t)2 * M * sizeof(float), stream);
    count_edges<<<(E + 255) / 256, 256, 0, stream>>>(dstv, et, invcnt, E, M);
    finalize_cnt<<<(2 * M + 255) / 256, 256, 0, stream>>>(invcnt, 2 * M);

    // Layer 1: emb -> out (relu)
    run_layer(emb, out, W1, root1, bias1, src, dstv, et, invcnt, T, M, E, true, stream);
    // Layer 2: out -> Y (relu)
    run_layer(out, Y, W2, root2, bias2, src, dstv, et, invcnt, T, M, E, true, stream);
    // Layer 3: Y -> out (no relu)
    run_layer(Y, out, W3, root3, bias3, src, dstv, et, invcnt, T, M, E, false, stream);
}

// Round 2
// 2377.828 us; speedup vs baseline: 2.0749x; 2.0749x over previous
//
#include <hip/hip_runtime.h>

// RGCN 3-layer forward on MI355X.
// R1: replace atomic scatter with CSR-sorted gather aggregation.
//   Preprocess (per call): count edges per (rel,dst) -> invcnt + exclusive
//   scan -> offsets[2M+1]; atomic-ticket fill -> sorted[E] (src per slot).
//   Per layer: out = x@root + bias (GEMM); for each relation r:
//     T = x@W[r] (GEMM), then per-node gather: out[d] += invc[r][d] * sum T[src].
//   ReLU fused into the rel=1 aggregation pass.
// f32 vector GEMM still (bf16 MFMA is the next step).

#define D 384
#define BM 64
#define BN 64
#define BK 16

__global__ __launch_bounds__(256) void gemm_bias_f32(
    const float* __restrict__ A, const float* __restrict__ B,
    const float* __restrict__ bias, float* __restrict__ C, int M)
{
    // A: [M, D] row-major; B: [D, D] row-major (k rows, n cols); C: [M, D]
    __shared__ float As[BK][BM];      // transposed A tile: As[k][m]
    __shared__ float Bs[BK][BN + 4];  // Bs[k][n], padded

    const int tid = threadIdx.x;
    const int bm = blockIdx.x * BM;
    const int bn = blockIdx.y * BN;
    const int ty = tid >> 4;          // 0..15
    const int tx = tid & 15;          // 0..15

    const int ar = tid >> 2;          // 0..63  (m within tile)
    const int ak = (tid & 3) << 2;    // 0,4,8,12 (k within tile)
    const int bkr = tid >> 4;         // 0..15 (k within tile)
    const int bnc = (tid & 15) << 2;  // 0..60 (n within tile)

    const int arow = bm + ar;

    float acc[4][4] = {};

    for (int k0 = 0; k0 < D; k0 += BK) {
        float4 av = make_float4(0.f, 0.f, 0.f, 0.f);
        if (arow < M) av = *(const float4*)(A + (size_t)arow * D + k0 + ak);
        const float4 bv = *(const float4*)(B + (size_t)(k0 + bkr) * D + bn + bnc);

        __syncthreads();
        As[ak + 0][ar] = av.x;
        As[ak + 1][ar] = av.y;
        As[ak + 2][ar] = av.z;
        As[ak + 3][ar] = av.w;
        *(float4*)(&Bs[bkr][bnc]) = bv;
        __syncthreads();

#pragma unroll
        for (int k = 0; k < BK; ++k) {
            const float a0 = As[k][ty * 4 + 0];
            const float a1 = As[k][ty * 4 + 1];
            const float a2 = As[k][ty * 4 + 2];
            const float a3 = As[k][ty * 4 + 3];
            const float b0 = Bs[k][tx * 4 + 0];
            const float b1 = Bs[k][tx * 4 + 1];
            const float b2 = Bs[k][tx * 4 + 2];
            const float b3 = Bs[k][tx * 4 + 3];
            acc[0][0] += a0 * b0; acc[0][1] += a0 * b1; acc[0][2] += a0 * b2; acc[0][3] += a0 * b3;
            acc[1][0] += a1 * b0; acc[1][1] += a1 * b1; acc[1][2] += a1 * b2; acc[1][3] += a1 * b3;
            acc[2][0] += a2 * b0; acc[2][1] += a2 * b1; acc[2][2] += a2 * b2; acc[2][3] += a2 * b3;
            acc[3][0] += a3 * b0; acc[3][1] += a3 * b1; acc[3][2] += a3 * b2; acc[3][3] += a3 * b3;
        }
    }

    float badd[4] = {0.f, 0.f, 0.f, 0.f};
    if (bias) {
#pragma unroll
        for (int j = 0; j < 4; ++j) badd[j] = bias[bn + tx * 4 + j];
    }
#pragma unroll
    for (int i = 0; i < 4; ++i) {
        const int row = bm + ty * 4 + i;
        if (row < M) {
            float* cp = C + (size_t)row * D + bn + tx * 4;
            float4 v;
            v.x = acc[i][0] + badd[0];
            v.y = acc[i][1] + badd[1];
            v.z = acc[i][2] + badd[2];
            v.w = acc[i][3] + badd[3];
            *(float4*)cp = v;
        }
    }
}

// ---- preprocessing: CSR by (rel, dst) ----

__global__ __launch_bounds__(256) void count_edges(
    const int* __restrict__ dst, const int* __restrict__ et,
    int* __restrict__ cntI, int E, int M)
{
    const int e = blockIdx.x * blockDim.x + threadIdx.x;
    if (e < E) atomicAdd(&cntI[(size_t)et[e] * M + dst[e]], 1);
}

__global__ __launch_bounds__(256) void finalize_cnt(
    const int* __restrict__ cntI, float* __restrict__ invc, int n)
{
    const int i = blockIdx.x * blockDim.x + threadIdx.x;
    if (i < n) invc[i] = 1.0f / (float)max(cntI[i], 1);
}

// single-block exclusive scan over n elements -> offs[0..n], offs[n] = total
__global__ __launch_bounds__(1024) void scan_offsets(
    const int* __restrict__ hist, int* __restrict__ offs, int n)
{
    __shared__ int tmp[1024];
    const int tid = threadIdx.x;
    int carry = 0;
    for (int base = 0; base < n; base += 1024) {
        const int i = base + tid;
        const int v = (i < n) ? hist[i] : 0;
        tmp[tid] = v;
        __syncthreads();
#pragma unroll
        for (int off = 1; off < 1024; off <<= 1) {
            const int add = (tid >= off) ? tmp[tid - off] : 0;
            __syncthreads();
            tmp[tid] += add;
            __syncthreads();
        }
        if (i < n) offs[i] = carry + (tmp[tid] - v);
        carry += tmp[1023];   // uniform across threads
        __syncthreads();      // protect tmp[1023] read from next-iter write
    }
    if (tid == 0) offs[n] = carry;
}

__global__ __launch_bounds__(256) void fill_sorted(
    const int* __restrict__ src, const int* __restrict__ dst,
    const int* __restrict__ et, const int* __restrict__ offs,
    int* __restrict__ cursor, int* __restrict__ sorted, int E, int M)
{
    const int e = blockIdx.x * blockDim.x + threadIdx.x;
    if (e < E) {
        const int key = et[e] * M + dst[e];
        const int pos = offs[key] + atomicAdd(&cursor[key], 1);
        sorted[pos] = src[e];
    }
}

// ---- aggregation: gather per node, no atomics ----
// 96 threads per node (thread j owns float4 at j*4), 2 nodes per 192-block.
__global__ __launch_bounds__(192) void aggregate_rel(
    const float* __restrict__ T, const int* __restrict__ sorted,
    const int* __restrict__ offs, const float* __restrict__ invc,
    float* __restrict__ out, int M, int relu)
{
    const int g = threadIdx.x / 96;
    const int j = (threadIdx.x % 96) << 2;
    const int d = blockIdx.x * 2 + g;
    if (d >= M) return;

    const int beg = offs[d];
    const int end = offs[d + 1];
    float4 acc = make_float4(0.f, 0.f, 0.f, 0.f);
    for (int i = beg; i < end; ++i) {
        const int s = sorted[i];
        const float4 v = *(const float4*)(T + (size_t)s * D + j);
        acc.x += v.x; acc.y += v.y; acc.z += v.z; acc.w += v.w;
    }
    const float ic = invc[d];
    float* o = out + (size_t)d * D + j;
    float4 ov = *(const float4*)o;
    ov.x += acc.x * ic;
    ov.y += acc.y * ic;
    ov.z += acc.z * ic;
    ov.w += acc.w * ic;
    if (relu) {
        ov.x = fmaxf(ov.x, 0.f);
        ov.y = fmaxf(ov.y, 0.f);
        ov.z = fmaxf(ov.z, 0.f);
        ov.w = fmaxf(ov.w, 0.f);
    }
    *(float4*)o = ov;
}

static void run_layer(const float* xin, float* xout, const float* W,
                      const float* root, const float* bias,
                      const int* sorted, const int* offs, const float* invcnt,
                      float* T, int M, bool relu, hipStream_t stream)
{
    dim3 gg((M + BM - 1) / BM, D / BN);
    gemm_bias_f32<<<gg, 256, 0, stream>>>(xin, root, bias, xout, M);
    const int ab = (M + 1) / 2;
    for (int r = 0; r < 2; ++r) {
        gemm_bias_f32<<<gg, 256, 0, stream>>>(xin, W + (size_t)r * D * D, nullptr, T, M);
        const int do_relu = (relu && r == 1) ? 1 : 0;
        aggregate_rel<<<ab, 192, 0, stream>>>(
            T, sorted, offs + (size_t)r * M, invcnt + (size_t)r * M, xout, M, do_relu);
    }
}

extern "C" void kernel_launch(void* const* d_in, const int* in_sizes, int n_in,
                              void* d_out, int out_size, void* d_ws, size_t ws_size,
                              hipStream_t stream)
{
    const float* emb  = (const float*)d_in[0];
    const int*   eidx = (const int*)d_in[1];   // [2, E]
    const int*   et   = (const int*)d_in[2];   // [E]
    const float* W1   = (const float*)d_in[3];
    const float* root1= (const float*)d_in[4];
    const float* bias1= (const float*)d_in[5];
    const float* W2   = (const float*)d_in[6];
    const float* root2= (const float*)d_in[7];
    const float* bias2= (const float*)d_in[8];
    const float* W3   = (const float*)d_in[9];
    const float* root3= (const float*)d_in[10];
    const float* bias3= (const float*)d_in[11];

    float* out = (float*)d_out;

    const int M = in_sizes[0] / D;   // 50000
    const int E = in_sizes[1] / 2;   // 200000
    const int* src = eidx;
    const int* dstv = eidx + E;

    // Workspace layout:
    // Y [M*D] f32 | T [M*D] f32 | invcnt [2M] f32 | cntI [2M] i32 (reused as
    // cursor) | offs [2M+1] i32 | sorted [E] i32
    float* Y = (float*)d_ws;
    float* T = Y + (size_t)M * D;
    float* invcnt = T + (size_t)M * D;
    int* cntI = (int*)(invcnt + (size_t)2 * M);
    int* offs = cntI + (size_t)2 * M;
    int* sorted = offs + (size_t)2 * M + 1;

    // --- preprocessing (depends only on edge_index / edge_type) ---
    hipMemsetAsync(cntI, 0, (size_t)2 * M * sizeof(int), stream);
    count_edges<<<(E + 255) / 256, 256, 0, stream>>>(dstv, et, cntI, E, M);
    finalize_cnt<<<(2 * M + 255) / 256, 256, 0, stream>>>(cntI, invcnt, 2 * M);
    scan_offsets<<<1, 1024, 0, stream>>>(cntI, offs, 2 * M);
    hipMemsetAsync(cntI, 0, (size_t)2 * M * sizeof(int), stream);  // reuse as cursor
    fill_sorted<<<(E + 255) / 256, 256, 0, stream>>>(src, dstv, et, offs, cntI, sorted, E, M);

    // --- layers: emb -> out (relu), out -> Y (relu), Y -> out ---
    run_layer(emb, out, W1, root1, bias1, sorted, offs, invcnt, T, M, true, stream);
    run_layer(out, Y, W2, root2, bias2, sorted, offs, invcnt, T, M, true, stream);
    run_layer(Y, out, W3, root3, bias3, sorted, offs, invcnt, T, M, false, stream);
}

// Round 3
// 704.993 us; speedup vs baseline: 6.9982x; 3.3728x over previous
//
#include <hip/hip_runtime.h>
#include <hip/hip_bf16.h>

// RGCN 3-layer forward on MI355X — R2: bf16 MFMA fused GEMM.
//   Per call: CSR preprocess (as R1); weights -> concatenated B^T bf16
//   [1152,384] per layer; emb -> bf16.
//   Per layer: TC[M,1152]bf16 = Xb @ [root|W0|W1] (one MFMA GEMM);
//   aggregate_all: out[d] = relu(TC[d,0:384]+bias + ic0*sum TC[s,384:768]
//                                + ic1*sum TC[s,768:1152]); writes bf16 Xb
//   (layers 1,2) or f32 d_out (layer 3).

#define D 384
#define NC 1152
#define BM 128
#define BN 128
#define BK 32

typedef __attribute__((ext_vector_type(8))) short short8;
typedef __attribute__((ext_vector_type(4))) float floatx4;
typedef unsigned int uint;
typedef unsigned short ushort;

__device__ __forceinline__ void load_lds16(const void* g, void* l) {
    __builtin_amdgcn_global_load_lds(
        (const __attribute__((address_space(1))) void*)g,
        (__attribute__((address_space(3))) void*)l, 16, 0, 0);
}

__device__ __forceinline__ ushort f2bf(float x) {
    __hip_bfloat16 h = __float2bfloat16(x);
    return *reinterpret_cast<ushort*>(&h);
}

__device__ __forceinline__ uint pack2(float a, float b) {
    return (uint)f2bf(a) | ((uint)f2bf(b) << 16);
}

// ---- bf16 MFMA GEMM: C[M,NC] = A[M,D] @ BT[NC,D]^T  (all bf16, f32 acc) ----
__global__ __launch_bounds__(256) void gemm_bf16_mfma(
    const ushort* __restrict__ A, const ushort* __restrict__ BT,
    ushort* __restrict__ C, int M)
{
    __shared__ alignas(16) ushort As[BM * BK];
    __shared__ alignas(16) ushort Bs[BN * BK];

    const int tid = threadIdx.x;
    const int wave = tid >> 6;
    const int lane = tid & 63;
    const int bm = blockIdx.x * BM;
    const int bn = blockIdx.y * BN;
    const int wr = wave >> 1;      // wave row 0..1 (64-row half)
    const int wc = wave & 1;       // wave col 0..1 (64-col half)
    const int l15 = lane & 15;
    const int k8 = lane >> 4;      // 0..3

    floatx4 acc[4][4] = {};

    for (int k0 = 0; k0 < D; k0 += BK) {
        __syncthreads();
        // stage 128x32 bf16 tiles (8 KB each) via global_load_lds width 16.
        // wave w, iter i covers LDS bytes [(i*4+w)*1024, +1024); lane adds L*16.
#pragma unroll
        for (int i = 0; i < 2; ++i) {
            const int region = i * 4 + wave;
            const int chunk = region * 64 + lane;   // 16B chunk id, 0..511
            const int row = chunk >> 2;             // 0..127
            const int c16 = chunk & 3;              // 16B group within 64B row
            const int ga = min(bm + row, M - 1);    // clamp partial M tile
            load_lds16(A + (size_t)ga * D + k0 + c16 * 8, As + (size_t)region * 512);
            load_lds16(BT + (size_t)(bn + row) * D + k0 + c16 * 8, Bs + (size_t)region * 512);
        }
        __syncthreads();

        short8 af[4], bf[4];
#pragma unroll
        for (int mi = 0; mi < 4; ++mi) {
            const int m = wr * 64 + mi * 16 + l15;
            af[mi] = *(const short8*)(As + m * BK + k8 * 8);
        }
#pragma unroll
        for (int ni = 0; ni < 4; ++ni) {
            const int n = wc * 64 + ni * 16 + l15;
            bf[ni] = *(const short8*)(Bs + n * BK + k8 * 8);
        }
#pragma unroll
        for (int mi = 0; mi < 4; ++mi)
#pragma unroll
            for (int ni = 0; ni < 4; ++ni)
                acc[mi][ni] = __builtin_amdgcn_mfma_f32_16x16x32_bf16(
                    af[mi], bf[ni], acc[mi][ni], 0, 0, 0);
    }

    // epilogue: C/D layout col=lane&15, row=(lane>>4)*4+reg
#pragma unroll
    for (int mi = 0; mi < 4; ++mi) {
#pragma unroll
        for (int reg = 0; reg < 4; ++reg) {
            const int row = bm + wr * 64 + mi * 16 + k8 * 4 + reg;
            if (row < M) {
#pragma unroll
                for (int ni = 0; ni < 4; ++ni) {
                    const int col = bn + wc * 64 + ni * 16 + l15;
                    C[(size_t)row * NC + col] = f2bf(acc[mi][ni][reg]);
                }
            }
        }
    }
}

// ---- preprocessing: CSR by (rel, dst) ----

__global__ __launch_bounds__(256) void count_edges(
    const int* __restrict__ dst, const int* __restrict__ et,
    int* __restrict__ cntI, int E, int M)
{
    const int e = blockIdx.x * blockDim.x + threadIdx.x;
    if (e < E) atomicAdd(&cntI[(size_t)et[e] * M + dst[e]], 1);
}

__global__ __launch_bounds__(256) void finalize_cnt(
    const int* __restrict__ cntI, float* __restrict__ invc, int n)
{
    const int i = blockIdx.x * blockDim.x + threadIdx.x;
    if (i < n) invc[i] = 1.0f / (float)max(cntI[i], 1);
}

__global__ __launch_bounds__(1024) void scan_offsets(
    const int* __restrict__ hist, int* __restrict__ offs, int n)
{
    __shared__ int tmp[1024];
    const int tid = threadIdx.x;
    int carry = 0;
    for (int base = 0; base < n; base += 1024) {
        const int i = base + tid;
        const int v = (i < n) ? hist[i] : 0;
        tmp[tid] = v;
        __syncthreads();
#pragma unroll
        for (int off = 1; off < 1024; off <<= 1) {
            const int add = (tid >= off) ? tmp[tid - off] : 0;
            __syncthreads();
            tmp[tid] += add;
            __syncthreads();
        }
        if (i < n) offs[i] = carry + (tmp[tid] - v);
        carry += tmp[1023];
        __syncthreads();
    }
    if (tid == 0) offs[n] = carry;
}

__global__ __launch_bounds__(256) void fill_sorted(
    const int* __restrict__ src, const int* __restrict__ dst,
    const int* __restrict__ et, const int* __restrict__ offs,
    int* __restrict__ cursor, int* __restrict__ sorted, int E, int M)
{
    const int e = blockIdx.x * blockDim.x + threadIdx.x;
    if (e < E) {
        const int key = et[e] * M + dst[e];
        const int pos = offs[key] + atomicAdd(&cursor[key], 1);
        sorted[pos] = src[e];
    }
}

// ---- weights -> concatenated B^T bf16 [NC, D] per layer ----
__global__ __launch_bounds__(256) void build_bt(
    const float* __restrict__ root1, const float* __restrict__ W1,
    const float* __restrict__ root2, const float* __restrict__ W2,
    const float* __restrict__ root3, const float* __restrict__ W3,
    ushort* __restrict__ BT)
{
    __shared__ float tile[32][33];
    const int l = blockIdx.z;
    const float* root = (l == 0) ? root1 : (l == 1) ? root2 : root3;
    const float* W    = (l == 0) ? W1    : (l == 1) ? W2    : W3;
    const int kt = blockIdx.x * 32;    // k tile base, 0..383
    const int nt = blockIdx.y * 32;    // n tile base, 0..1151
    const int tx = threadIdx.x & 31;
    const int ty = threadIdx.x >> 5;   // 0..7
    const float* srcm;
    int noff;
    if (nt < D)          { srcm = root;      noff = 0; }
    else if (nt < 2 * D) { srcm = W;         noff = D; }
    else                 { srcm = W + D * D; noff = 2 * D; }
    const int n = nt - noff + tx;
#pragma unroll
    for (int i = 0; i < 4; ++i) {
        const int k = kt + ty + i * 8;
        tile[ty + i * 8][tx] = srcm[(size_t)k * D + n];
    }
    __syncthreads();
    ushort* dst = BT + (size_t)l * NC * D;
#pragma unroll
    for (int i = 0; i < 4; ++i) {
        const int nn = nt + ty + i * 8;
        const int kk = kt + tx;
        dst[(size_t)nn * D + kk] = f2bf(tile[tx][ty + i * 8]);
    }
}

__global__ __launch_bounds__(256) void cast_f32_to_bf16(
    const float* __restrict__ x, ushort* __restrict__ y, int n4)
{
    const int i = blockIdx.x * blockDim.x + threadIdx.x;
    if (i < n4) {
        const float4 v = ((const float4*)x)[i];
        uint2 o;
        o.x = pack2(v.x, v.y);
        o.y = pack2(v.z, v.w);
        ((uint2*)y)[i] = o;
    }
}

// ---- fused aggregation: one wave per node, both relations + root + bias ----
__global__ __launch_bounds__(256) void aggregate_all(
    const ushort* __restrict__ TC, const int* __restrict__ sorted,
    const int* __restrict__ offs, const float* __restrict__ invc,
    const float* __restrict__ bias, ushort* __restrict__ outb,
    float* __restrict__ outf, int M, int relu)
{
    const int wave = threadIdx.x >> 6;
    const int lane = threadIdx.x & 63;
    const int d = blockIdx.x * 4 + wave;
    if (d >= M) return;

    float v[6];
    {
        const uint* rp = (const uint*)(TC + (size_t)d * NC);  // root slice, 192 uints
#pragma unroll
        for (int p = 0; p < 3; ++p) {
            const uint b = rp[lane + 64 * p];
            const float2 bb = *(const float2*)(bias + (lane + 64 * p) * 2);
            v[2 * p]     = __uint_as_float(b << 16) + bb.x;
            v[2 * p + 1] = __uint_as_float(b & 0xffff0000u) + bb.y;
        }
    }
#pragma unroll
    for (int r = 0; r < 2; ++r) {
        const int key = r * M + d;
        const int beg = offs[key], end = offs[key + 1];
        float g[6] = {0.f, 0.f, 0.f, 0.f, 0.f, 0.f};
        for (int i = beg; i < end; ++i) {
            const int s = sorted[i];
            const uint* tp = (const uint*)(TC + (size_t)s * NC + D + r * D);
#pragma unroll
            for (int p = 0; p < 3; ++p) {
                const uint b = tp[lane + 64 * p];
                g[2 * p]     += __uint_as_float(b << 16);
                g[2 * p + 1] += __uint_as_float(b & 0xffff0000u);
            }
        }
        const float ic = invc[key];
#pragma unroll
        for (int j = 0; j < 6; ++j) v[j] += ic * g[j];
    }
    if (relu) {
#pragma unroll
        for (int j = 0; j < 6; ++j) v[j] = fmaxf(v[j], 0.f);
    }
    if (outb) {
        uint* op = (uint*)(outb + (size_t)d * D);
#pragma unroll
        for (int p = 0; p < 3; ++p) op[lane + 64 * p] = pack2(v[2 * p], v[2 * p + 1]);
    } else {
        float2* op = (float2*)(outf + (size_t)d * D);
#pragma unroll
        for (int p = 0; p < 3; ++p)
            op[lane + 64 * p] = make_float2(v[2 * p], v[2 * p + 1]);
    }
}

extern "C" void kernel_launch(void* const* d_in, const int* in_sizes, int n_in,
                              void* d_out, int out_size, void* d_ws, size_t ws_size,
                              hipStream_t stream)
{
    const float* emb   = (const float*)d_in[0];
    const int*   eidx  = (const int*)d_in[1];
    const int*   et    = (const int*)d_in[2];
    const float* W1    = (const float*)d_in[3];
    const float* root1 = (const float*)d_in[4];
    const float* bias1 = (const float*)d_in[5];
    const float* W2    = (const float*)d_in[6];
    const float* root2 = (const float*)d_in[7];
    const float* bias2 = (const float*)d_in[8];
    const float* W3    = (const float*)d_in[9];
    const float* root3 = (const float*)d_in[10];
    const float* bias3 = (const float*)d_in[11];

    float* out = (float*)d_out;
    const int M = in_sizes[0] / D;   // 50000
    const int E = in_sizes[1] / 2;   // 200000
    const int* src  = eidx;
    const int* dstv = eidx + E;

    // Workspace: TC[M*NC]bf16 | Xb[M*D]bf16 | BT[3*NC*D]bf16 |
    //            invcnt[2M]f32 | cntI[2M]i32 | offs[2M+1]i32 | sorted[E]i32
    char* w = (char*)d_ws;
    ushort* TC = (ushort*)w;          w += (size_t)M * NC * 2;
    ushort* Xb = (ushort*)w;          w += (size_t)M * D * 2;
    ushort* BT = (ushort*)w;          w += (size_t)3 * NC * D * 2;
    float* invcnt = (float*)w;        w += (size_t)2 * M * 4;
    int* cntI = (int*)w;              w += (size_t)2 * M * 4;
    int* offs = (int*)w;              w += ((size_t)2 * M + 1) * 4;
    int* sorted = (int*)w;

    // --- preprocessing ---
    hipMemsetAsync(cntI, 0, (size_t)2 * M * sizeof(int), stream);
    count_edges<<<(E + 255) / 256, 256, 0, stream>>>(dstv, et, cntI, E, M);
    finalize_cnt<<<(2 * M + 255) / 256, 256, 0, stream>>>(cntI, invcnt, 2 * M);
    scan_offsets<<<1, 1024, 0, stream>>>(cntI, offs, 2 * M);
    hipMemsetAsync(cntI, 0, (size_t)2 * M * sizeof(int), stream);
    fill_sorted<<<(E + 255) / 256, 256, 0, stream>>>(src, dstv, et, offs, cntI, sorted, E, M);

    build_bt<<<dim3(D / 32, NC / 32, 3), 256, 0, stream>>>(root1, W1, root2, W2, root3, W3, BT);
    cast_f32_to_bf16<<<(M * D / 4 + 255) / 256, 256, 0, stream>>>(emb, Xb, M * D / 4);

    const dim3 gg((M + BM - 1) / BM, NC / BN);
    const float* biases[3] = {bias1, bias2, bias3};
    for (int l = 0; l < 3; ++l) {
        gemm_bf16_mfma<<<gg, 256, 0, stream>>>(Xb, BT + (size_t)l * NC * D, TC, M);
        const bool last = (l == 2);
        aggregate_all<<<(M + 3) / 4, 256, 0, stream>>>(
            TC, sorted, offs, invcnt, biases[l],
            last ? nullptr : Xb, last ? out : nullptr, M, last ? 0 : 1);
    }
}

// Round 4
// 549.544 us; speedup vs baseline: 8.9778x; 1.2829x over previous
//
#include <hip/hip_runtime.h>
#include <hip/hip_bf16.h>

// RGCN 3-layer forward on MI355X — R3: parallel hierarchical scan
// (R2's single-block scan_offsets was 173 us = 25% of runtime).
//   Per call: CSR preprocess; weights -> concatenated B^T bf16 [1152,384]
//   per layer; emb -> bf16.
//   Per layer: TC[M,1152]bf16 = Xb @ [root|W0|W1] (one MFMA GEMM);
//   aggregate_all: out[d] = relu(TC[d,0:384]+bias + ic0*sum TC[s,384:768]
//                                + ic1*sum TC[s,768:1152]).

#define D 384
#define NC 1152
#define BM 128
#define BN 128
#define BK 32

typedef __attribute__((ext_vector_type(8))) short short8;
typedef __attribute__((ext_vector_type(4))) float floatx4;
typedef unsigned int uint;
typedef unsigned short ushort;

__device__ __forceinline__ void load_lds16(const void* g, void* l) {
    __builtin_amdgcn_global_load_lds(
        (const __attribute__((address_space(1))) void*)g,
        (__attribute__((address_space(3))) void*)l, 16, 0, 0);
}

__device__ __forceinline__ ushort f2bf(float x) {
    __hip_bfloat16 h = __float2bfloat16(x);
    return *reinterpret_cast<ushort*>(&h);
}

__device__ __forceinline__ uint pack2(float a, float b) {
    return (uint)f2bf(a) | ((uint)f2bf(b) << 16);
}

// ---- bf16 MFMA GEMM: C[M,NC] = A[M,D] @ BT[NC,D]^T  (all bf16, f32 acc) ----
__global__ __launch_bounds__(256) void gemm_bf16_mfma(
    const ushort* __restrict__ A, const ushort* __restrict__ BT,
    ushort* __restrict__ C, int M)
{
    __shared__ alignas(16) ushort As[BM * BK];
    __shared__ alignas(16) ushort Bs[BN * BK];

    const int tid = threadIdx.x;
    const int wave = tid >> 6;
    const int lane = tid & 63;
    const int bm = blockIdx.x * BM;
    const int bn = blockIdx.y * BN;
    const int wr = wave >> 1;      // wave row 0..1 (64-row half)
    const int wc = wave & 1;       // wave col 0..1 (64-col half)
    const int l15 = lane & 15;
    const int k8 = lane >> 4;      // 0..3

    floatx4 acc[4][4] = {};

    for (int k0 = 0; k0 < D; k0 += BK) {
        __syncthreads();
        // stage 128x32 bf16 tiles (8 KB each) via global_load_lds width 16.
#pragma unroll
        for (int i = 0; i < 2; ++i) {
            const int region = i * 4 + wave;
            const int chunk = region * 64 + lane;   // 16B chunk id, 0..511
            const int row = chunk >> 2;             // 0..127
            const int c16 = chunk & 3;              // 16B group within 64B row
            const int ga = min(bm + row, M - 1);    // clamp partial M tile
            load_lds16(A + (size_t)ga * D + k0 + c16 * 8, As + (size_t)region * 512);
            load_lds16(BT + (size_t)(bn + row) * D + k0 + c16 * 8, Bs + (size_t)region * 512);
        }
        __syncthreads();

        short8 af[4], bf[4];
#pragma unroll
        for (int mi = 0; mi < 4; ++mi) {
            const int m = wr * 64 + mi * 16 + l15;
            af[mi] = *(const short8*)(As + m * BK + k8 * 8);
        }
#pragma unroll
        for (int ni = 0; ni < 4; ++ni) {
            const int n = wc * 64 + ni * 16 + l15;
            bf[ni] = *(const short8*)(Bs + n * BK + k8 * 8);
        }
#pragma unroll
        for (int mi = 0; mi < 4; ++mi)
#pragma unroll
            for (int ni = 0; ni < 4; ++ni)
                acc[mi][ni] = __builtin_amdgcn_mfma_f32_16x16x32_bf16(
                    af[mi], bf[ni], acc[mi][ni], 0, 0, 0);
    }

    // epilogue: C/D layout col=lane&15, row=(lane>>4)*4+reg
#pragma unroll
    for (int mi = 0; mi < 4; ++mi) {
#pragma unroll
        for (int reg = 0; reg < 4; ++reg) {
            const int row = bm + wr * 64 + mi * 16 + k8 * 4 + reg;
            if (row < M) {
#pragma unroll
                for (int ni = 0; ni < 4; ++ni) {
                    const int col = bn + wc * 64 + ni * 16 + l15;
                    C[(size_t)row * NC + col] = f2bf(acc[mi][ni][reg]);
                }
            }
        }
    }
}

// ---- preprocessing: CSR by (rel, dst) ----

__global__ __launch_bounds__(256) void count_edges(
    const int* __restrict__ dst, const int* __restrict__ et,
    int* __restrict__ cntI, int E, int M)
{
    const int e = blockIdx.x * blockDim.x + threadIdx.x;
    if (e < E) atomicAdd(&cntI[(size_t)et[e] * M + dst[e]], 1);
}

__global__ __launch_bounds__(256) void finalize_cnt(
    const int* __restrict__ cntI, float* __restrict__ invc, int n)
{
    const int i = blockIdx.x * blockDim.x + threadIdx.x;
    if (i < n) invc[i] = 1.0f / (float)max(cntI[i], 1);
}

// ---- 3-kernel hierarchical exclusive scan (n ~ 100k) ----
// 1) per-block (1024-wide) exclusive scan + block sums
__global__ __launch_bounds__(1024) void scan_local(
    const int* __restrict__ hist, int* __restrict__ offs,
    int* __restrict__ bsums, int n)
{
    __shared__ int tmp[1024];
    const int tid = threadIdx.x;
    const int i = blockIdx.x * 1024 + tid;
    const int v = (i < n) ? hist[i] : 0;
    tmp[tid] = v;
    __syncthreads();
#pragma unroll
    for (int off = 1; off < 1024; off <<= 1) {
        const int add = (tid >= off) ? tmp[tid - off] : 0;
        __syncthreads();
        tmp[tid] += add;
        __syncthreads();
    }
    if (i < n) offs[i] = tmp[tid] - v;   // exclusive within block
    if (tid == 1023) bsums[blockIdx.x] = tmp[1023];
}

// 2) single-block exclusive scan of block sums (nb <= 1024); writes total
__global__ __launch_bounds__(1024) void scan_bsums(
    int* __restrict__ bsums, int* __restrict__ total_out, int nb)
{
    __shared__ int tmp[1024];
    const int tid = threadIdx.x;
    const int v = (tid < nb) ? bsums[tid] : 0;
    tmp[tid] = v;
    __syncthreads();
#pragma unroll
    for (int off = 1; off < 1024; off <<= 1) {
        const int add = (tid >= off) ? tmp[tid - off] : 0;
        __syncthreads();
        tmp[tid] += add;
        __syncthreads();
    }
    if (tid < nb) bsums[tid] = tmp[tid] - v;   // exclusive
    if (tid == 1023) *total_out = tmp[1023];   // grand total
}

// 3) add scanned block sums
__global__ __launch_bounds__(1024) void scan_add(
    int* __restrict__ offs, const int* __restrict__ bsums, int n)
{
    const int i = blockIdx.x * 1024 + threadIdx.x;
    if (i < n) offs[i] += bsums[blockIdx.x];
}

__global__ __launch_bounds__(256) void fill_sorted(
    const int* __restrict__ src, const int* __restrict__ dst,
    const int* __restrict__ et, const int* __restrict__ offs,
    int* __restrict__ cursor, int* __restrict__ sorted, int E, int M)
{
    const int e = blockIdx.x * blockDim.x + threadIdx.x;
    if (e < E) {
        const int key = et[e] * M + dst[e];
        const int pos = offs[key] + atomicAdd(&cursor[key], 1);
        sorted[pos] = src[e];
    }
}

// ---- weights -> concatenated B^T bf16 [NC, D] per layer ----
__global__ __launch_bounds__(256) void build_bt(
    const float* __restrict__ root1, const float* __restrict__ W1,
    const float* __restrict__ root2, const float* __restrict__ W2,
    const float* __restrict__ root3, const float* __restrict__ W3,
    ushort* __restrict__ BT)
{
    __shared__ float tile[32][33];
    const int l = blockIdx.z;
    const float* root = (l == 0) ? root1 : (l == 1) ? root2 : root3;
    const float* W    = (l == 0) ? W1    : (l == 1) ? W2    : W3;
    const int kt = blockIdx.x * 32;    // k tile base, 0..383
    const int nt = blockIdx.y * 32;    // n tile base, 0..1151
    const int tx = threadIdx.x & 31;
    const int ty = threadIdx.x >> 5;   // 0..7
    const float* srcm;
    int noff;
    if (nt < D)          { srcm = root;      noff = 0; }
    else if (nt < 2 * D) { srcm = W;         noff = D; }
    else                 { srcm = W + D * D; noff = 2 * D; }
    const int n = nt - noff + tx;
#pragma unroll
    for (int i = 0; i < 4; ++i) {
        const int k = kt + ty + i * 8;
        tile[ty + i * 8][tx] = srcm[(size_t)k * D + n];
    }
    __syncthreads();
    ushort* dst = BT + (size_t)l * NC * D;
#pragma unroll
    for (int i = 0; i < 4; ++i) {
        const int nn = nt + ty + i * 8;
        const int kk = kt + tx;
        dst[(size_t)nn * D + kk] = f2bf(tile[tx][ty + i * 8]);
    }
}

__global__ __launch_bounds__(256) void cast_f32_to_bf16(
    const float* __restrict__ x, ushort* __restrict__ y, int n4)
{
    const int i = blockIdx.x * blockDim.x + threadIdx.x;
    if (i < n4) {
        const float4 v = ((const float4*)x)[i];
        uint2 o;
        o.x = pack2(v.x, v.y);
        o.y = pack2(v.z, v.w);
        ((uint2*)y)[i] = o;
    }
}

// ---- fused aggregation: one wave per node, both relations + root + bias ----
__global__ __launch_bounds__(256) void aggregate_all(
    const ushort* __restrict__ TC, const int* __restrict__ sorted,
    const int* __restrict__ offs, const float* __restrict__ invc,
    const float* __restrict__ bias, ushort* __restrict__ outb,
    float* __restrict__ outf, int M, int relu)
{
    const int wave = threadIdx.x >> 6;
    const int lane = threadIdx.x & 63;
    const int d = blockIdx.x * 4 + wave;
    if (d >= M) return;

    float v[6];
    {
        const uint* rp = (const uint*)(TC + (size_t)d * NC);  // root slice
#pragma unroll
        for (int p = 0; p < 3; ++p) {
            const uint b = rp[lane + 64 * p];
            const float2 bb = *(const float2*)(bias + (lane + 64 * p) * 2);
            v[2 * p]     = __uint_as_float(b << 16) + bb.x;
            v[2 * p + 1] = __uint_as_float(b & 0xffff0000u) + bb.y;
        }
    }
#pragma unroll
    for (int r = 0; r < 2; ++r) {
        const int key = r * M + d;
        const int beg = offs[key], end = offs[key + 1];
        float g[6] = {0.f, 0.f, 0.f, 0.f, 0.f, 0.f};
        for (int i = beg; i < end; ++i) {
            const int s = sorted[i];
            const uint* tp = (const uint*)(TC + (size_t)s * NC + D + r * D);
#pragma unroll
            for (int p = 0; p < 3; ++p) {
                const uint b = tp[lane + 64 * p];
                g[2 * p]     += __uint_as_float(b << 16);
                g[2 * p + 1] += __uint_as_float(b & 0xffff0000u);
            }
        }
        const float ic = invc[key];
#pragma unroll
        for (int j = 0; j < 6; ++j) v[j] += ic * g[j];
    }
    if (relu) {
#pragma unroll
        for (int j = 0; j < 6; ++j) v[j] = fmaxf(v[j], 0.f);
    }
    if (outb) {
        uint* op = (uint*)(outb + (size_t)d * D);
#pragma unroll
        for (int p = 0; p < 3; ++p) op[lane + 64 * p] = pack2(v[2 * p], v[2 * p + 1]);
    } else {
        float2* op = (float2*)(outf + (size_t)d * D);
#pragma unroll
        for (int p = 0; p < 3; ++p)
            op[lane + 64 * p] = make_float2(v[2 * p], v[2 * p + 1]);
    }
}

extern "C" void kernel_launch(void* const* d_in, const int* in_sizes, int n_in,
                              void* d_out, int out_size, void* d_ws, size_t ws_size,
                              hipStream_t stream)
{
    const float* emb   = (const float*)d_in[0];
    const int*   eidx  = (const int*)d_in[1];
    const int*   et    = (const int*)d_in[2];
    const float* W1    = (const float*)d_in[3];
    const float* root1 = (const float*)d_in[4];
    const float* bias1 = (const float*)d_in[5];
    const float* W2    = (const float*)d_in[6];
    const float* root2 = (const float*)d_in[7];
    const float* bias2 = (const float*)d_in[8];
    const float* W3    = (const float*)d_in[9];
    const float* root3 = (const float*)d_in[10];
    const float* bias3 = (const float*)d_in[11];

    float* out = (float*)d_out;
    const int M = in_sizes[0] / D;   // 50000
    const int E = in_sizes[1] / 2;   // 200000
    const int* src  = eidx;
    const int* dstv = eidx + E;

    const int n = 2 * M;                      // scan length
    const int nb = (n + 1023) / 1024;         // scan blocks (<=1024)

    // Workspace: TC[M*NC]bf16 | Xb[M*D]bf16 | BT[3*NC*D]bf16 |
    //            invcnt[2M]f32 | cntI[2M]i32 | offs[2M+1]i32 | sorted[E]i32 |
    //            bsums[nb]i32
    char* w = (char*)d_ws;
    ushort* TC = (ushort*)w;          w += (size_t)M * NC * 2;
    ushort* Xb = (ushort*)w;          w += (size_t)M * D * 2;
    ushort* BT = (ushort*)w;          w += (size_t)3 * NC * D * 2;
    float* invcnt = (float*)w;        w += (size_t)n * 4;
    int* cntI = (int*)w;              w += (size_t)n * 4;
    int* offs = (int*)w;              w += ((size_t)n + 1) * 4;
    int* sorted = (int*)w;            w += (size_t)E * 4;
    int* bsums = (int*)w;

    // --- preprocessing ---
    hipMemsetAsync(cntI, 0, (size_t)n * sizeof(int), stream);
    count_edges<<<(E + 255) / 256, 256, 0, stream>>>(dstv, et, cntI, E, M);
    finalize_cnt<<<(n + 255) / 256, 256, 0, stream>>>(cntI, invcnt, n);
    scan_local<<<nb, 1024, 0, stream>>>(cntI, offs, bsums, n);
    scan_bsums<<<1, 1024, 0, stream>>>(bsums, offs + n, nb);
    scan_add<<<nb, 1024, 0, stream>>>(offs, bsums, n);
    hipMemsetAsync(cntI, 0, (size_t)n * sizeof(int), stream);
    fill_sorted<<<(E + 255) / 256, 256, 0, stream>>>(src, dstv, et, offs, cntI, sorted, E, M);

    build_bt<<<dim3(D / 32, NC / 32, 3), 256, 0, stream>>>(root1, W1, root2, W2, root3, W3, BT);
    cast_f32_to_bf16<<<(M * D / 4 + 255) / 256, 256, 0, stream>>>(emb, Xb, M * D / 4);

    const dim3 gg((M + BM - 1) / BM, NC / BN);
    const float* biases[3] = {bias1, bias2, bias3};
    for (int l = 0; l < 3; ++l) {
        gemm_bf16_mfma<<<gg, 256, 0, stream>>>(Xb, BT + (size_t)l * NC * D, TC, M);
        const bool last = (l == 2);
        aggregate_all<<<(M + 3) / 4, 256, 0, stream>>>(
            TC, sorted, offs, invcnt, biases[l],
            last ? nullptr : Xb, last ? out : nullptr, M, last ? 0 : 1);
    }
}

// Round 5
// 498.679 us; speedup vs baseline: 9.8935x; 1.1020x over previous
//
#include <hip/hip_runtime.h>
#include <hip/hip_bf16.h>

// RGCN 3-layer forward on MI355X — R4: GEMM overhaul.
//   (a) XCD-aware block remap: all 9 N-tiles of an M-tile go to one XCD
//       consecutively -> A-tile L2 reuse (FETCH 173 -> ~45 MB).
//   (b) BK=64, 128 B LDS rows + XOR chunk swizzle (cs ^ (row&7)) ->
//       conflict-free ds_read_b128 fragment loads.
//   Rest as R3: CSR preprocess, fused [root|W0|W1] GEMM per layer,
//   one-wave-per-node aggregation.

#define D 384
#define NC 1152
#define BM 128
#define BN 128
#define BK 64
#define NTILES 9   // NC / BN

typedef __attribute__((ext_vector_type(8))) short short8;
typedef __attribute__((ext_vector_type(4))) float floatx4;
typedef unsigned int uint;
typedef unsigned short ushort;

__device__ __forceinline__ void load_lds16(const void* g, void* l) {
    __builtin_amdgcn_global_load_lds(
        (const __attribute__((address_space(1))) void*)g,
        (__attribute__((address_space(3))) void*)l, 16, 0, 0);
}

__device__ __forceinline__ ushort f2bf(float x) {
    __hip_bfloat16 h = __float2bfloat16(x);
    return *reinterpret_cast<ushort*>(&h);
}

__device__ __forceinline__ uint pack2(float a, float b) {
    return (uint)f2bf(a) | ((uint)f2bf(b) << 16);
}

// ---- bf16 MFMA GEMM: C[M,NC] = A[M,D] @ BT[NC,D]^T  (all bf16, f32 acc) ----
// 1D grid, size 8 * NTILES * ceil(Mtiles/8). XCD-aware remap inside.
__global__ __launch_bounds__(256) void gemm_bf16_mfma(
    const ushort* __restrict__ A, const ushort* __restrict__ BT,
    ushort* __restrict__ C, int M)
{
    // 128 rows x 64 k bf16 = 128 B rows = 8 chunks of 16 B, XOR-swizzled.
    __shared__ alignas(16) ushort As[BM * BK];
    __shared__ alignas(16) ushort Bs[BN * BK];

    const int b = blockIdx.x;
    const int xcd = b & 7;
    const int t = b >> 3;
    const int bnt = t % NTILES;
    const int bmt = (t / NTILES) * 8 + xcd;
    const int Mtiles = (M + BM - 1) / BM;
    if (bmt >= Mtiles) return;          // block-uniform: safe before barriers
    const int bm = bmt * BM;
    const int bn = bnt * BN;

    const int tid = threadIdx.x;
    const int wave = tid >> 6;
    const int lane = tid & 63;
    const int wr = wave >> 1;      // wave row 0..1 (64-row half)
    const int wc = wave & 1;       // wave col 0..1 (64-col half)
    const int l15 = lane & 15;
    const int k8 = lane >> 4;      // 0..3

    floatx4 acc[4][4] = {};

    for (int k0 = 0; k0 < D; k0 += BK) {
        __syncthreads();
        // stage 128x64 tiles (16 KB each): 1024 chunks of 16 B per matrix,
        // 4 rounds x 256 threads. LDS slot (row, cs) <- global chunk
        // (row, cs ^ (row & 7)).
#pragma unroll
        for (int j = 0; j < 4; ++j) {
            const int chunk = j * 256 + wave * 64 + lane;  // 0..1023
            const int row = chunk >> 3;                    // 0..127
            const int cs = chunk & 7;                      // slot chunk in row
            const int gc = cs ^ (row & 7);                 // global chunk
            const int ga = min(bm + row, M - 1);           // clamp partial tile
            load_lds16(A + (size_t)ga * D + k0 + gc * 8, As + (size_t)chunk * 8);
            load_lds16(BT + (size_t)(bn + row) * D + k0 + gc * 8, Bs + (size_t)chunk * 8);
        }
        __syncthreads();

#pragma unroll
        for (int p = 0; p < 2; ++p) {        // two 32-k phases of BK=64
            short8 af[4], bfr[4];
            const int kc = p * 4 + k8;       // global 16B-chunk in row, 0..7
#pragma unroll
            for (int mi = 0; mi < 4; ++mi) {
                const int m = wr * 64 + mi * 16 + l15;
                af[mi] = *(const short8*)(As + m * BK + (kc ^ (m & 7)) * 8);
            }
#pragma unroll
            for (int ni = 0; ni < 4; ++ni) {
                const int n = wc * 64 + ni * 16 + l15;
                bfr[ni] = *(const short8*)(Bs + n * BK + (kc ^ (n & 7)) * 8);
            }
#pragma unroll
            for (int mi = 0; mi < 4; ++mi)
#pragma unroll
                for (int ni = 0; ni < 4; ++ni)
                    acc[mi][ni] = __builtin_amdgcn_mfma_f32_16x16x32_bf16(
                        af[mi], bfr[ni], acc[mi][ni], 0, 0, 0);
        }
    }

    // epilogue: C/D layout col=lane&15, row=(lane>>4)*4+reg
#pragma unroll
    for (int mi = 0; mi < 4; ++mi) {
#pragma unroll
        for (int reg = 0; reg < 4; ++reg) {
            const int row = bm + wr * 64 + mi * 16 + k8 * 4 + reg;
            if (row < M) {
#pragma unroll
                for (int ni = 0; ni < 4; ++ni) {
                    const int col = bn + wc * 64 + ni * 16 + l15;
                    C[(size_t)row * NC + col] = f2bf(acc[mi][ni][reg]);
                }
            }
        }
    }
}

// ---- preprocessing: CSR by (rel, dst) ----

__global__ __launch_bounds__(256) void count_edges(
    const int* __restrict__ dst, const int* __restrict__ et,
    int* __restrict__ cntI, int E, int M)
{
    const int e = blockIdx.x * blockDim.x + threadIdx.x;
    if (e < E) atomicAdd(&cntI[(size_t)et[e] * M + dst[e]], 1);
}

__global__ __launch_bounds__(256) void finalize_cnt(
    const int* __restrict__ cntI, float* __restrict__ invc, int n)
{
    const int i = blockIdx.x * blockDim.x + threadIdx.x;
    if (i < n) invc[i] = 1.0f / (float)max(cntI[i], 1);
}

// ---- 3-kernel hierarchical exclusive scan (n ~ 100k) ----
__global__ __launch_bounds__(1024) void scan_local(
    const int* __restrict__ hist, int* __restrict__ offs,
    int* __restrict__ bsums, int n)
{
    __shared__ int tmp[1024];
    const int tid = threadIdx.x;
    const int i = blockIdx.x * 1024 + tid;
    const int v = (i < n) ? hist[i] : 0;
    tmp[tid] = v;
    __syncthreads();
#pragma unroll
    for (int off = 1; off < 1024; off <<= 1) {
        const int add = (tid >= off) ? tmp[tid - off] : 0;
        __syncthreads();
        tmp[tid] += add;
        __syncthreads();
    }
    if (i < n) offs[i] = tmp[tid] - v;
    if (tid == 1023) bsums[blockIdx.x] = tmp[1023];
}

__global__ __launch_bounds__(1024) void scan_bsums(
    int* __restrict__ bsums, int* __restrict__ total_out, int nb)
{
    __shared__ int tmp[1024];
    const int tid = threadIdx.x;
    const int v = (tid < nb) ? bsums[tid] : 0;
    tmp[tid] = v;
    __syncthreads();
#pragma unroll
    for (int off = 1; off < 1024; off <<= 1) {
        const int add = (tid >= off) ? tmp[tid - off] : 0;
        __syncthreads();
        tmp[tid] += add;
        __syncthreads();
    }
    if (tid < nb) bsums[tid] = tmp[tid] - v;
    if (tid == 1023) *total_out = tmp[1023];
}

__global__ __launch_bounds__(1024) void scan_add(
    int* __restrict__ offs, const int* __restrict__ bsums, int n)
{
    const int i = blockIdx.x * 1024 + threadIdx.x;
    if (i < n) offs[i] += bsums[blockIdx.x];
}

__global__ __launch_bounds__(256) void fill_sorted(
    const int* __restrict__ src, const int* __restrict__ dst,
    const int* __restrict__ et, const int* __restrict__ offs,
    int* __restrict__ cursor, int* __restrict__ sorted, int E, int M)
{
    const int e = blockIdx.x * blockDim.x + threadIdx.x;
    if (e < E) {
        const int key = et[e] * M + dst[e];
        const int pos = offs[key] + atomicAdd(&cursor[key], 1);
        sorted[pos] = src[e];
    }
}

// ---- weights -> concatenated B^T bf16 [NC, D] per layer ----
__global__ __launch_bounds__(256) void build_bt(
    const float* __restrict__ root1, const float* __restrict__ W1,
    const float* __restrict__ root2, const float* __restrict__ W2,
    const float* __restrict__ root3, const float* __restrict__ W3,
    ushort* __restrict__ BT)
{
    __shared__ float tile[32][33];
    const int l = blockIdx.z;
    const float* root = (l == 0) ? root1 : (l == 1) ? root2 : root3;
    const float* W    = (l == 0) ? W1    : (l == 1) ? W2    : W3;
    const int kt = blockIdx.x * 32;
    const int nt = blockIdx.y * 32;
    const int tx = threadIdx.x & 31;
    const int ty = threadIdx.x >> 5;
    const float* srcm;
    int noff;
    if (nt < D)          { srcm = root;      noff = 0; }
    else if (nt < 2 * D) { srcm = W;         noff = D; }
    else                 { srcm = W + D * D; noff = 2 * D; }
    const int n = nt - noff + tx;
#pragma unroll
    for (int i = 0; i < 4; ++i) {
        const int k = kt + ty + i * 8;
        tile[ty + i * 8][tx] = srcm[(size_t)k * D + n];
    }
    __syncthreads();
    ushort* dst = BT + (size_t)l * NC * D;
#pragma unroll
    for (int i = 0; i < 4; ++i) {
        const int nn = nt + ty + i * 8;
        const int kk = kt + tx;
        dst[(size_t)nn * D + kk] = f2bf(tile[tx][ty + i * 8]);
    }
}

__global__ __launch_bounds__(256) void cast_f32_to_bf16(
    const float* __restrict__ x, ushort* __restrict__ y, int n4)
{
    const int i = blockIdx.x * blockDim.x + threadIdx.x;
    if (i < n4) {
        const float4 v = ((const float4*)x)[i];
        uint2 o;
        o.x = pack2(v.x, v.y);
        o.y = pack2(v.z, v.w);
        ((uint2*)y)[i] = o;
    }
}

// ---- fused aggregation: one wave per node, both relations + root + bias ----
__global__ __launch_bounds__(256) void aggregate_all(
    const ushort* __restrict__ TC, const int* __restrict__ sorted,
    const int* __restrict__ offs, const float* __restrict__ invc,
    const float* __restrict__ bias, ushort* __restrict__ outb,
    float* __restrict__ outf, int M, int relu)
{
    const int wave = threadIdx.x >> 6;
    const int lane = threadIdx.x & 63;
    const int d = blockIdx.x * 4 + wave;
    if (d >= M) return;

    float v[6];
    {
        const uint* rp = (const uint*)(TC + (size_t)d * NC);
#pragma unroll
        for (int p = 0; p < 3; ++p) {
            const uint b = rp[lane + 64 * p];
            const float2 bb = *(const float2*)(bias + (lane + 64 * p) * 2);
            v[2 * p]     = __uint_as_float(b << 16) + bb.x;
            v[2 * p + 1] = __uint_as_float(b & 0xffff0000u) + bb.y;
        }
    }
#pragma unroll
    for (int r = 0; r < 2; ++r) {
        const int key = r * M + d;
        const int beg = offs[key], end = offs[key + 1];
        float g[6] = {0.f, 0.f, 0.f, 0.f, 0.f, 0.f};
        for (int i = beg; i < end; ++i) {
            const int s = sorted[i];
            const uint* tp = (const uint*)(TC + (size_t)s * NC + D + r * D);
#pragma unroll
            for (int p = 0; p < 3; ++p) {
                const uint b = tp[lane + 64 * p];
                g[2 * p]     += __uint_as_float(b << 16);
                g[2 * p + 1] += __uint_as_float(b & 0xffff0000u);
            }
        }
        const float ic = invc[key];
#pragma unroll
        for (int j = 0; j < 6; ++j) v[j] += ic * g[j];
    }
    if (relu) {
#pragma unroll
        for (int j = 0; j < 6; ++j) v[j] = fmaxf(v[j], 0.f);
    }
    if (outb) {
        uint* op = (uint*)(outb + (size_t)d * D);
#pragma unroll
        for (int p = 0; p < 3; ++p) op[lane + 64 * p] = pack2(v[2 * p], v[2 * p + 1]);
    } else {
        float2* op = (float2*)(outf + (size_t)d * D);
#pragma unroll
        for (int p = 0; p < 3; ++p)
            op[lane + 64 * p] = make_float2(v[2 * p], v[2 * p + 1]);
    }
}

extern "C" void kernel_launch(void* const* d_in, const int* in_sizes, int n_in,
                              void* d_out, int out_size, void* d_ws, size_t ws_size,
                              hipStream_t stream)
{
    const float* emb   = (const float*)d_in[0];
    const int*   eidx  = (const int*)d_in[1];
    const int*   et    = (const int*)d_in[2];
    const float* W1    = (const float*)d_in[3];
    const float* root1 = (const float*)d_in[4];
    const float* bias1 = (const float*)d_in[5];
    const float* W2    = (const float*)d_in[6];
    const float* root2 = (const float*)d_in[7];
    const float* bias2 = (const float*)d_in[8];
    const float* W3    = (const float*)d_in[9];
    const float* root3 = (const float*)d_in[10];
    const float* bias3 = (const float*)d_in[11];

    float* out = (float*)d_out;
    const int M = in_sizes[0] / D;   // 50000
    const int E = in_sizes[1] / 2;   // 200000
    const int* src  = eidx;
    const int* dstv = eidx + E;

    const int n = 2 * M;
    const int nb = (n + 1023) / 1024;

    // Workspace: TC[M*NC]bf16 | Xb[M*D]bf16 | BT[3*NC*D]bf16 |
    //            invcnt[2M]f32 | cntI[2M]i32 | offs[2M+1]i32 | sorted[E]i32 |
    //            bsums[nb]i32
    char* w = (char*)d_ws;
    ushort* TC = (ushort*)w;          w += (size_t)M * NC * 2;
    ushort* Xb = (ushort*)w;          w += (size_t)M * D * 2;
    ushort* BT = (ushort*)w;          w += (size_t)3 * NC * D * 2;
    float* invcnt = (float*)w;        w += (size_t)n * 4;
    int* cntI = (int*)w;              w += (size_t)n * 4;
    int* offs = (int*)w;              w += ((size_t)n + 1) * 4;
    int* sorted = (int*)w;            w += (size_t)E * 4;
    int* bsums = (int*)w;

    // --- preprocessing ---
    hipMemsetAsync(cntI, 0, (size_t)n * sizeof(int), stream);
    count_edges<<<(E + 255) / 256, 256, 0, stream>>>(dstv, et, cntI, E, M);
    finalize_cnt<<<(n + 255) / 256, 256, 0, stream>>>(cntI, invcnt, n);
    scan_local<<<nb, 1024, 0, stream>>>(cntI, offs, bsums, n);
    scan_bsums<<<1, 1024, 0, stream>>>(bsums, offs + n, nb);
    scan_add<<<nb, 1024, 0, stream>>>(offs, bsums, n);
    hipMemsetAsync(cntI, 0, (size_t)n * sizeof(int), stream);
    fill_sorted<<<(E + 255) / 256, 256, 0, stream>>>(src, dstv, et, offs, cntI, sorted, E, M);

    build_bt<<<dim3(D / 32, NC / 32, 3), 256, 0, stream>>>(root1, W1, root2, W2, root3, W3, BT);
    cast_f32_to_bf16<<<(M * D / 4 + 255) / 256, 256, 0, stream>>>(emb, Xb, M * D / 4);

    // GEMM grid: 8 XCD slots x NTILES x ceil(Mtiles/8)
    const int Mtiles = (M + BM - 1) / BM;
    const int gemm_blocks = 8 * NTILES * ((Mtiles + 7) / 8);
    const float* biases[3] = {bias1, bias2, bias3};
    for (int l = 0; l < 3; ++l) {
        gemm_bf16_mfma<<<gemm_blocks, 256, 0, stream>>>(Xb, BT + (size_t)l * NC * D, TC, M);
        const bool last = (l == 2);
        aggregate_all<<<(M + 3) / 4, 256, 0, stream>>>(
            TC, sorted, offs, invcnt, biases[l],
            last ? nullptr : Xb, last ? out : nullptr, M, last ? 0 : 1);
    }
}